// Round 13
// baseline (69.490 us; speedup 1.0000x reference)
//
#include <hip/hip_runtime.h>
#include <math.h>

#define B_DIM 256
#define M_DIM 256
#define C_DIM 1024
#define C4    256            // C/4 float4 per row
#define UM_OFF (B_DIM * C_DIM)                       // 262144 floats
#define KL_OFF (UM_OFF + B_DIM * M_DIM * C_DIM)      // 67371008 floats
#define SCALE  0.03125f      // 1/sqrt(1024)

__device__ __forceinline__ float dot4(float4 a, float4 b) {
    return a.x*b.x + a.y*b.y + a.z*b.z + a.w*b.w;
}
__device__ __forceinline__ float wsum(float v) {
    #pragma unroll
    for (int off = 32; off; off >>= 1) v += __shfl_xor(v, off, 64);
    return v;
}
__device__ __forceinline__ float wmax(float v) {
    #pragma unroll
    for (int off = 32; off; off >>= 1) v = fmaxf(v, __shfl_xor(v, off, 64));
    return v;
}
__device__ __forceinline__ float4 blend9(float4 v, float4 xr) {
    return make_float4(0.9f*v.x + 0.1f*xr.x, 0.9f*v.y + 0.1f*xr.y,
                       0.9f*v.z + 0.1f*xr.z, 0.9f*v.w + 0.1f*xr.w);
}

// ---------------- Kernel A: role-split. 8448 blocks x 256 thr.
// bid <  256 : prefix block for batch b=bid (sims/softmax/z/kl, publish idx).
// bid >= 256 : raw stream block j=bid-256 -> batch j>>5, rows (j&31)*8..+7.
__global__ __launch_bounds__(256) void tm_main(const float* __restrict__ x,
                                               const float* __restrict__ mem,
                                               float* __restrict__ out,
                                               int* __restrict__ idx_ws) {
    const int bid = blockIdx.x;
    const int t = threadIdx.x;
    const float4* mem4 = (const float4*)mem;

    if (bid >= B_DIM) {
        // ================= raw stream role (no idx dependency) =============
        const int j  = bid - B_DIM;     // 0..8191
        const int b  = j >> 5;
        const int m0 = (j & 31) << 3;   // 0,8,...,248
        const float4* src = mem4 + (m0 << 8) + t;
        float4 r0 = src[0 << 8];
        float4 r1 = src[1 << 8];
        float4 r2 = src[2 << 8];
        float4 r3 = src[3 << 8];
        float4 r4 = src[4 << 8];
        float4 r5 = src[5 << 8];
        float4 r6 = src[6 << 8];
        float4 r7 = src[7 << 8];
        float4* dst = (float4*)(out + UM_OFF) + ((size_t)b << 16) + (m0 << 8) + t;
        dst[0 << 8] = r0;
        dst[1 << 8] = r1;
        dst[2 << 8] = r2;
        dst[3 << 8] = r3;
        dst[4 << 8] = r4;
        dst[5 << 8] = r5;
        dst[6 << 8] = r6;
        dst[7 << 8] = r7;
        return;
    }

    // ================= prefix role: batch b = bid =======================
    const int b = bid;
    const int lane = t & 63;
    const int wv = t >> 6;     // 0..3

    __shared__ float4 s_x[C4];        // 4 KB
    __shared__ float  s_sims[M_DIM];  // 1 KB
    __shared__ float  s_attn[M_DIM];  // 1 KB
    __shared__ float  s_w0[4], s_w1[4];

    float4 xv = ((const float4*)(x + (size_t)b * C_DIM))[t];
    s_x[t] = xv;
    __syncthreads();                                   // barrier 1

    // sims: wave wv owns m in [wv*64, wv*64+64)
    const float4 xr0 = s_x[lane];
    const float4 xr1 = s_x[lane + 64];
    const float4 xr2 = s_x[lane + 128];
    const float4 xr3 = s_x[lane + 192];
    #pragma unroll 4
    for (int i = 0; i < 64; ++i) {
        const int m = (wv << 6) | i;
        const float4* mr = mem4 + (m << 8);
        float acc = dot4(mr[lane],     xr0) + dot4(mr[lane+64],  xr1)
                  + dot4(mr[lane+128], xr2) + dot4(mr[lane+192], xr3);
        acc = wsum(acc);
        if (lane == 0) s_sims[m] = acc;
    }
    __syncthreads();                                   // barrier 2

    // per-wave redundant softmax (zero barriers; identical in all 4 waves)
    const float v0 = s_sims[lane];
    const float v1 = s_sims[lane + 64];
    const float v2 = s_sims[lane + 128];
    const float v3 = s_sims[lane + 192];
    const float n2 = wsum(dot4(xr0,xr0) + dot4(xr1,xr1) + dot4(xr2,xr2) + dot4(xr3,xr3));

    // argmax, first-max tie-break (like np.argmax)
    float av = v0; int am = lane;
    if (v1 > av) { av = v1; am = lane + 64; }
    if (v2 > av) { av = v2; am = lane + 128; }
    if (v3 > av) { av = v3; am = lane + 192; }
    #pragma unroll
    for (int off = 32; off; off >>= 1) {
        float ov = __shfl_xor(av, off, 64);
        int   oi = __shfl_xor(am, off, 64);
        if (ov > av || (ov == av && oi < am)) { av = ov; am = oi; }
    }
    const int idx = am;
    if (t == 0) idx_ws[b] = idx;       // consumed by tm_fix next dispatch
    const float fused = 0.9f * av + 0.1f * n2;

    float s0 = ((lane      ) == idx ? fused : v0) * SCALE;
    float s1 = ((lane +  64) == idx ? fused : v1) * SCALE;
    float s2 = ((lane + 128) == idx ? fused : v2) * SCALE;
    float s3 = ((lane + 192) == idx ? fused : v3) * SCALE;
    const float mx = wmax(fmaxf(fmaxf(s0, s1), fmaxf(s2, s3)));
    const float e0 = expf(s0 - mx), e1 = expf(s1 - mx);
    const float e2 = expf(s2 - mx), e3 = expf(s3 - mx);
    const float inv = 1.0f / wsum(e0 + e1 + e2 + e3);
    const float a0 = e0 * inv, a1 = e1 * inv, a2 = e2 * inv, a3 = e3 * inv;

    if (wv == 0) {
        s_attn[lane]       = a0;
        s_attn[lane + 64]  = a1;
        s_attn[lane + 128] = a2;
        s_attn[lane + 192] = a3;
    }

    float aidx;
    if      (idx <  64) aidx = __shfl(a0, idx,       64);
    else if (idx < 128) aidx = __shfl(a1, idx - 64,  64);
    else if (idx < 192) aidx = __shfl(a2, idx - 128, 64);
    else                aidx = __shfl(a3, idx - 192, 64);
    aidx *= 0.1f;
    __syncthreads();                                   // barrier 3 (attn visible)

    // z pass: thread t owns float4 column t
    float4 z = make_float4(0.f, 0.f, 0.f, 0.f);
    #pragma unroll 8
    for (int m = 0; m < M_DIM; ++m) {
        const float a = s_attn[m];
        float4 v = mem4[(m << 8) + t];
        z.x = fmaf(a, v.x, z.x);
        z.y = fmaf(a, v.y, z.y);
        z.z = fmaf(a, v.z, z.z);
        z.w = fmaf(a, v.w, z.w);
    }
    float4 sl = mem4[(idx << 8) + t];
    float4 d = make_float4(xv.x - sl.x, xv.y - sl.y, xv.z - sl.z, xv.w - sl.w);
    const float dwp = dot4(d, d);
    z.x = fmaf(aidx, d.x, z.x);
    z.y = fmaf(aidx, d.y, z.y);
    z.z = fmaf(aidx, d.z, z.z);
    z.w = fmaf(aidx, d.w, z.w);
    float ex = z.x - xv.x, ey = z.y - xv.y, ez = z.z - xv.z, ew = z.w - xv.w;
    const float drp = ex*ex + ey*ey + ez*ez + ew*ew;
    ((float4*)out)[(size_t)b * C4 + t] = z;

    const float sw = wsum(dwp);
    const float sr = wsum(drp);
    if (lane == 0) { s_w0[wv] = sw; s_w1[wv] = sr; }
    __syncthreads();                                   // barrier 4
    if (t == 0)
        out[KL_OFF + b] = 0.5f * (s_w0[0]+s_w0[1]+s_w0[2]+s_w0[3]
                                + s_w1[0]+s_w1[1]+s_w1[2]+s_w1[3]);
}

// ---------------- Kernel B: blend-row fixup. 256 blocks x 256 thr, ~1 MB.
__global__ __launch_bounds__(256) void tm_fix(const float* __restrict__ x,
                                              const float* __restrict__ mem,
                                              const int* __restrict__ idx_ws,
                                              float* __restrict__ out_um) {
    const int b = blockIdx.x;
    const int t = threadIdx.x;
    const int idx = idx_ws[b];
    float4 sl = ((const float4*)mem)[(idx << 8) + t];
    float4 xv = ((const float4*)(x + (size_t)b * C_DIM))[t];
    ((float4*)out_um)[((size_t)b << 16) + (idx << 8) + t] = blend9(sl, xv);
}

extern "C" void kernel_launch(void* const* d_in, const int* in_sizes, int n_in,
                              void* d_out, int out_size, void* d_ws, size_t ws_size,
                              hipStream_t stream) {
    const float* x   = (const float*)d_in[0];   // input_encoded [B, C]
    const float* mem = (const float*)d_in[1];   // memory_mean  [M, C]
    float* out = (float*)d_out;
    int* idx_ws = (int*)d_ws;

    tm_main<<<dim3(B_DIM + 8192), dim3(256), 0, stream>>>(x, mem, out, idx_ws);
    tm_fix<<<dim3(B_DIM), dim3(256), 0, stream>>>(x, mem, idx_ws, out + UM_OFF);
}